// Round 13
// baseline (831.955 us; speedup 1.0000x reference)
//
#include <hip/hip_runtime.h>
#include <math.h>

// Problem constants: B=8, Cin=64, Cout=128, H=W=128, KS=3, N=9, K=576
#define KDIM 576

// ---------------- zero-fill x_t (border padding) ----------------
__global__ void k_zero(float4* __restrict__ p, int n4) {
    int i = blockIdx.x * 256 + threadIdx.x;
    if (i < n4) p[i] = make_float4(0.f, 0.f, 0.f, 0.f);
}

// ---------------- pad + NCHW->NHWC transpose ----------------
__global__ __launch_bounds__(256) void k_pad_transpose(
    const float* __restrict__ x, float* __restrict__ x_t) {
    __shared__ float lds[128 * 65];
    int b = blockIdx.x >> 7;
    int h = blockIdx.x & 127;
    for (int e = threadIdx.x; e < 64 * 128; e += 256) {
        int ci = e >> 7, w = e & 127;
        lds[w * 65 + ci] = x[((b * 64 + ci) * 128 + h) * 128 + w];
    }
    __syncthreads();
    for (int e = threadIdx.x; e < 128 * 64; e += 256) {
        int w = e >> 6, ci = e & 63;
        x_t[((b * 130 + h + 1) * 130 + (w + 1)) * 64 + ci] = lds[w * 65 + ci];
    }
}

// ---------------- W_conv -> fp32 k-major, K permuted: Wkm[k'][co], k' = n*64+ci ----------------
__global__ void k_wct(const float* __restrict__ Wc, float* __restrict__ Wkm) {
    int e = blockIdx.x * 256 + threadIdx.x;
    if (e >= 128 * KDIM) return;
    int co = e & 127, kp = e >> 7;
    int n = kp >> 6, ci = kp & 63;
    Wkm[e] = Wc[co * KDIM + ci * 9 + n];
}

// ---------------- offset + mask 3x3 convs: wave-uniform 7-oc blocking ----------------
// wave q owns ocs {q*7 .. q*7+6} (q=3: 6 ocs); lane = wl. Per (ci,kx): 3 LDS reads
// amortized over up to 21 FMAs; weights are wave-uniform -> scalar loads.
__global__ __launch_bounds__(256) void k_offmask(
    const float* __restrict__ x_t, const float* __restrict__ Wp, const float* __restrict__ bp,
    const float* __restrict__ Wm, const float* __restrict__ bm,
    float* __restrict__ offs, float* __restrict__ mask) {
    __shared__ float lds[198 * 65];
    int t = blockIdx.x;
    int wt = t & 1, h = (t >> 1) & 127, b = t >> 8;
    int w0 = wt * 64;
    for (int e = threadIdx.x; e < 198 * 64; e += 256) {
        int chunk = e >> 6, ci = e & 63;
        int row = chunk / 66, col = chunk % 66;
        lds[chunk * 65 + ci] = x_t[((b * 130 + h + row) * 130 + (w0 + col)) * 64 + ci];
    }
    __syncthreads();

    int wl = threadIdx.x & 63;
    int q  = __builtin_amdgcn_readfirstlane(threadIdx.x >> 6);   // wave-uniform
    int oc0 = q * 7;
    int noc = (q == 3) ? 6 : 7;

    const float* wrows[7];
    #pragma unroll
    for (int j = 0; j < 7; ++j) {
        int oc = oc0 + j;
        wrows[j] = (oc < 18) ? (Wp + oc * KDIM) : (Wm + (oc - 18) * KDIM);
    }

    float acc[7] = {0.f, 0.f, 0.f, 0.f, 0.f, 0.f, 0.f};
    for (int ci = 0; ci < 64; ++ci) {
        #pragma unroll
        for (int kx = 0; kx < 3; ++kx) {
            float x0 = lds[(kx * 66 + wl + 0) * 65 + ci];
            float x1 = lds[(kx * 66 + wl + 1) * 65 + ci];
            float x2 = lds[(kx * 66 + wl + 2) * 65 + ci];
            #pragma unroll
            for (int j = 0; j < 7; ++j) {
                if (j < noc) {
                    const float* wk = wrows[j] + ci * 9 + kx * 3;
                    acc[j] += x0 * wk[0] + x1 * wk[1] + x2 * wk[2];
                }
            }
        }
    }

    int idx = ((b * 128 + h) * 128 + (w0 + wl));
    #pragma unroll
    for (int j = 0; j < 7; ++j) {
        if (j < noc) {
            int oc = oc0 + j;
            if (oc < 18) {
                offs[idx * 18 + oc] = acc[j] + bp[oc];
            } else {
                float v = acc[j] + bm[oc - 18];
                mask[idx * 9 + (oc - 18)] = 1.f / (1.f + __expf(-v));
            }
        }
    }
}

// ---------------- main: deformable sample -> LDS-staged-weight VALU dot ----------------
// block = 16 positions; grid = 8192, XCD-pinned. Weights staged in LDS in 9 chunks of
// 64 k' (32 KB) shared by all 4 waves: 4x less L2 traffic, immediate-offset ds_reads.
// Thread = (lane -> co pair 2*lane, pg = pos-group of 4). LDS 73.7 KB -> 2 blocks/CU.
__global__ __launch_bounds__(256, 2) void k_main(
    const float* __restrict__ x_t, const float* __restrict__ offs,
    const float* __restrict__ mask, const float* __restrict__ Wkm,
    float* __restrict__ out) {
    __shared__ __align__(16) float a_lds[16 * KDIM];   // 36864 B; reused as outst
    __shared__ __align__(16) float w_lds[64 * 128];    // 32768 B weight chunk
    __shared__ int    pi3[144 * 3];                    // lt, rb, dy
    __shared__ float4 pg4[144];

    int blk = blockIdx.x;
    int b  = blk & 7;                  // XCD swizzle: one batch per XCD
    int rem = blk >> 3;
    int h  = rem >> 3;
    int w0 = (rem & 7) * 16;
    int tid = threadIdx.x;

    // phase 1: sampling coords for 16 pos x 9 pts (proven math)
    if (tid < 144) {
        int e = tid;
        int pos = e / 9, n = e - pos * 9;
        int w = w0 + pos;
        int idx = ((b * 128 + h) * 128 + w);
        float ox = offs[idx * 18 + n];
        float oy = offs[idx * 18 + 9 + n];
        float mv = mask[idx * 9 + n];
        float px = ox + (float)(h + n / 3);
        float py = oy + (float)(w + n % 3);
        float flx = floorf(px), fly = floorf(py);
        float qltx = fminf(fmaxf(flx, 0.f), 129.f);
        float qlty = fminf(fmaxf(fly, 0.f), 129.f);
        float qrbx = fminf(fmaxf(flx + 1.f, 0.f), 129.f);
        float qrby = fminf(fmaxf(fly + 1.f, 0.f), 129.f);
        float pxc = fminf(fmaxf(px, 0.f), 129.f);
        float pyc = fminf(fmaxf(py, 0.f), 129.f);
        float glt = (1.f + qltx - pxc) * (1.f + qlty - pyc);
        float grb = (1.f - qrbx + pxc) * (1.f - qrby + pyc);
        float glb = (1.f + qltx - pxc) * (1.f - qrby + pyc);
        float grt = (1.f - qrbx + pxc) * (1.f + qlty - pyc);
        int ix_lt = (int)qltx, iy_lt = (int)qlty, ix_rb = (int)qrbx, iy_rb = (int)qrby;
        pi3[e * 3 + 0] = (ix_lt * 130 + iy_lt) * 64;
        pi3[e * 3 + 1] = (ix_rb * 130 + iy_rb) * 64;
        pi3[e * 3 + 2] = (iy_rb - iy_lt) * 64;
        pg4[e] = make_float4(glt * mv, grb * mv, glb * mv, grt * mv);
    }
    __syncthreads();

    // phase 2: gather+blend, a_lds[pos][k' = n*64 + ci] in fp32 (proven pattern)
    {
        const float* xb = x_t + (size_t)b * 130 * 130 * 64;
        int ci = tid & 63;
        for (int it = 0; it < 36; ++it) {
            int point = (tid >> 6) + it * 4;
            int pos = (point * 456) >> 12;          // point/9, exact for point<288
            int n = point - pos * 9;
            int lt = pi3[point * 3 + 0];
            int rb = pi3[point * 3 + 1];
            int dy = pi3[point * 3 + 2];
            float4 g = pg4[point];
            float v = g.x * xb[lt + ci] + g.y * xb[rb + ci] +
                      g.z * xb[lt + dy + ci] + g.w * xb[rb - dy + ci];
            a_lds[pos * KDIM + n * 64 + ci] = v;
        }
    }

    // phase 3: chunked dot. 9 chunks of 64 k'; weights staged in LDS once per block.
    int lane = tid & 63, pg = tid >> 6;
    int co0 = lane * 2;                              // thread's co pair
    float acc[2][4] = {{0.f, 0.f, 0.f, 0.f}, {0.f, 0.f, 0.f, 0.f}};
    for (int ch = 0; ch < 9; ++ch) {
        __syncthreads();                             // w_lds free (also closes phase 2 on ch=0)
        {
            const float4* src = (const float4*)(Wkm + ch * 8192);
            float4* dst = (float4*)w_lds;
            #pragma unroll
            for (int i = 0; i < 8; ++i) dst[tid + i * 256] = src[tid + i * 256];
        }
        __syncthreads();                             // chunk ready
        #pragma unroll 4
        for (int k4 = 0; k4 < 16; ++k4) {
            int kk = k4 * 4;
            float2 w0 = *(const float2*)&w_lds[(kk + 0) * 128 + co0];
            float2 w1 = *(const float2*)&w_lds[(kk + 1) * 128 + co0];
            float2 w2 = *(const float2*)&w_lds[(kk + 2) * 128 + co0];
            float2 w3 = *(const float2*)&w_lds[(kk + 3) * 128 + co0];
            #pragma unroll
            for (int p = 0; p < 4; ++p) {
                float4 a = *(const float4*)&a_lds[(pg * 4 + p) * KDIM + ch * 64 + kk];
                acc[0][p] += a.x * w0.x + a.y * w1.x + a.z * w2.x + a.w * w3.x;
                acc[1][p] += a.x * w0.y + a.y * w1.y + a.z * w2.y + a.w * w3.y;
            }
        }
    }
    __syncthreads();   // all a_lds reads done before aliasing overwrite

    // epilogue: stage via LDS, then coalesced global stores (proven path)
    float* outst = a_lds;                    // [128 co][17]
    #pragma unroll
    for (int c = 0; c < 2; ++c)
        #pragma unroll
        for (int p = 0; p < 4; ++p)
            outst[(co0 + c) * 17 + pg * 4 + p] = acc[c][p];
    __syncthreads();
    for (int e = tid; e < 2048; e += 256) {
        int co = e >> 4, wl = e & 15;
        out[((size_t)(b * 128 + co) * 16384) + h * 128 + w0 + wl] = outst[co * 17 + wl];
    }
}

// ---------------- BN stats: one block per (b, co) ----------------
__global__ __launch_bounds__(256) void k_stats(
    const float* __restrict__ out, float* __restrict__ partial) {
    __shared__ float s1[256], s2[256];
    int blk = blockIdx.x;
    const float4* p = (const float4*)(out + (size_t)blk * 16384);
    float a1 = 0.f, a2 = 0.f;
    for (int i = threadIdx.x; i < 4096; i += 256) {
        float4 v = p[i];
        a1 += v.x + v.y + v.z + v.w;
        a2 += v.x * v.x + v.y * v.y + v.z * v.z + v.w * v.w;
    }
    s1[threadIdx.x] = a1; s2[threadIdx.x] = a2;
    __syncthreads();
    for (int s = 128; s > 0; s >>= 1) {
        if (threadIdx.x < (unsigned)s) {
            s1[threadIdx.x] += s1[threadIdx.x + s];
            s2[threadIdx.x] += s2[threadIdx.x + s];
        }
        __syncthreads();
    }
    if (threadIdx.x == 0) { partial[blk] = s1[0]; partial[1024 + blk] = s2[0]; }
}

__global__ void k_finalize(const float* __restrict__ partial, const float* __restrict__ gamma,
                           const float* __restrict__ beta, float* __restrict__ sb) {
    int c = threadIdx.x;
    if (c < 128) {
        float s1 = 0.f, s2 = 0.f;
        for (int b = 0; b < 8; ++b) {
            s1 += partial[b * 128 + c];
            s2 += partial[1024 + b * 128 + c];
        }
        const float M = 131072.f;
        float mean = s1 / M;
        float var = fmaxf(s2 / M - mean * mean, 0.f);
        float sc = gamma[c] * rsqrtf(var + 1e-5f);
        sb[c] = sc;
        sb[128 + c] = beta[c] - mean * sc;
    }
}

__global__ void k_bnrelu(float* __restrict__ out, const float* __restrict__ sb) {
    int i = blockIdx.x * 256 + threadIdx.x;
    int c = (i >> 12) & 127;
    float4 v = ((float4*)out)[i];
    float sc = sb[c], bi = sb[128 + c];
    v.x = fmaxf(v.x * sc + bi, 0.f);
    v.y = fmaxf(v.y * sc + bi, 0.f);
    v.z = fmaxf(v.z * sc + bi, 0.f);
    v.w = fmaxf(v.w * sc + bi, 0.f);
    ((float4*)out)[i] = v;
}

extern "C" void kernel_launch(void* const* d_in, const int* in_sizes, int n_in,
                              void* d_out, int out_size, void* d_ws, size_t ws_size,
                              hipStream_t stream) {
    const float* x     = (const float*)d_in[0];
    const float* Wp    = (const float*)d_in[1];
    const float* bp    = (const float*)d_in[2];
    const float* Wm    = (const float*)d_in[3];
    const float* bm    = (const float*)d_in[4];
    const float* Wc    = (const float*)d_in[5];
    const float* gamma = (const float*)d_in[6];
    const float* beta  = (const float*)d_in[7];
    float* out = (float*)d_out;
    float* ws  = (float*)d_ws;

    // ws layout (floats)
    float* x_t     = ws;                         // 8,652,800
    float* Wkm     = x_t + 8652800;              // 73,728 (576*128 fp32, k-major)
    float* offs    = Wkm + 73728;                // 2,359,296
    float* mask    = offs + 2359296;             // 1,179,648
    float* partial = mask + 1179648;             // 2048
    float* sb      = partial + 2048;             // 256

    k_zero<<<8450, 256, 0, stream>>>((float4*)x_t, 2163200);
    k_pad_transpose<<<1024, 256, 0, stream>>>(x, x_t);
    k_wct<<<288, 256, 0, stream>>>(Wc, Wkm);
    k_offmask<<<2048, 256, 0, stream>>>(x_t, Wp, bp, Wm, bm, offs, mask);
    k_main<<<8192, 256, 0, stream>>>(x_t, offs, mask, Wkm, out);
    k_stats<<<1024, 256, 0, stream>>>(out, partial);
    k_finalize<<<1, 128, 0, stream>>>(partial, gamma, beta, sb);
    k_bnrelu<<<16384, 256, 0, stream>>>(out, sb);
}

// Round 14
// 723.511 us; speedup vs baseline: 1.1499x; 1.1499x over previous
//
#include <hip/hip_runtime.h>
#include <math.h>

// Problem constants: B=8, Cin=64, Cout=128, H=W=128, KS=3, N=9, K=576
#define KDIM 576

// ---------------- zero-fill x_t (border padding) ----------------
__global__ void k_zero(float4* __restrict__ p, int n4) {
    int i = blockIdx.x * 256 + threadIdx.x;
    if (i < n4) p[i] = make_float4(0.f, 0.f, 0.f, 0.f);
}

// ---------------- pad + NCHW->NHWC transpose ----------------
__global__ __launch_bounds__(256) void k_pad_transpose(
    const float* __restrict__ x, float* __restrict__ x_t) {
    __shared__ float lds[128 * 65];
    int b = blockIdx.x >> 7;
    int h = blockIdx.x & 127;
    for (int e = threadIdx.x; e < 64 * 128; e += 256) {
        int ci = e >> 7, w = e & 127;
        lds[w * 65 + ci] = x[((b * 64 + ci) * 128 + h) * 128 + w];
    }
    __syncthreads();
    for (int e = threadIdx.x; e < 128 * 64; e += 256) {
        int w = e >> 6, ci = e & 63;
        x_t[((b * 130 + h + 1) * 130 + (w + 1)) * 64 + ci] = lds[w * 65 + ci];
    }
}

// ---------------- W_conv -> fp32 k-major, K permuted: Wkm[k'][co], k' = n*64+ci ----------------
__global__ void k_wct(const float* __restrict__ Wc, float* __restrict__ Wkm) {
    int e = blockIdx.x * 256 + threadIdx.x;
    if (e >= 128 * KDIM) return;
    int co = e & 127, kp = e >> 7;
    int n = kp >> 6, ci = kp & 63;
    Wkm[e] = Wc[co * KDIM + ci * 9 + n];
}

// ---------------- offset + mask 3x3 convs: wave-uniform 7-oc blocking (R13-proven) ----------------
__global__ __launch_bounds__(256) void k_offmask(
    const float* __restrict__ x_t, const float* __restrict__ Wp, const float* __restrict__ bp,
    const float* __restrict__ Wm, const float* __restrict__ bm,
    float* __restrict__ offs, float* __restrict__ mask) {
    __shared__ float lds[198 * 65];
    int t = blockIdx.x;
    int wt = t & 1, h = (t >> 1) & 127, b = t >> 8;
    int w0 = wt * 64;
    for (int e = threadIdx.x; e < 198 * 64; e += 256) {
        int chunk = e >> 6, ci = e & 63;
        int row = chunk / 66, col = chunk % 66;
        lds[chunk * 65 + ci] = x_t[((b * 130 + h + row) * 130 + (w0 + col)) * 64 + ci];
    }
    __syncthreads();

    int wl = threadIdx.x & 63;
    int q  = __builtin_amdgcn_readfirstlane(threadIdx.x >> 6);
    int oc0 = q * 7;
    int noc = (q == 3) ? 6 : 7;

    const float* wrows[7];
    #pragma unroll
    for (int j = 0; j < 7; ++j) {
        int oc = oc0 + j;
        wrows[j] = (oc < 18) ? (Wp + oc * KDIM) : (Wm + (oc - 18) * KDIM);
    }

    float acc[7] = {0.f, 0.f, 0.f, 0.f, 0.f, 0.f, 0.f};
    for (int ci = 0; ci < 64; ++ci) {
        #pragma unroll
        for (int kx = 0; kx < 3; ++kx) {
            float x0 = lds[(kx * 66 + wl + 0) * 65 + ci];
            float x1 = lds[(kx * 66 + wl + 1) * 65 + ci];
            float x2 = lds[(kx * 66 + wl + 2) * 65 + ci];
            #pragma unroll
            for (int j = 0; j < 7; ++j) {
                if (j < noc) {
                    const float* wk = wrows[j] + ci * 9 + kx * 3;
                    acc[j] += x0 * wk[0] + x1 * wk[1] + x2 * wk[2];
                }
            }
        }
    }

    int idx = ((b * 128 + h) * 128 + (w0 + wl));
    #pragma unroll
    for (int j = 0; j < 7; ++j) {
        if (j < noc) {
            int oc = oc0 + j;
            if (oc < 18) {
                offs[idx * 18 + oc] = acc[j] + bp[oc];
            } else {
                float v = acc[j] + bm[oc - 18];
                mask[idx * 9 + (oc - 18)] = 1.f / (1.f + __expf(-v));
            }
        }
    }
}

// ---------------- main: deformable sample -> co-banded pipelined VALU dot ----------------
// block = 16 positions; grid = 8192, XCD-pinned; 4 blocks/CU (LDS 40896 B).
// Phase 3: wave wv owns cos [wv*32, wv*32+32); lane = (cl=co-in-band, ph=pos-half);
// thread = 8 pos x 1 co. Each wave streams only its 73.7 KB weight slice (4x cut).
__global__ __launch_bounds__(256, 4) void k_main(
    const float* __restrict__ x_t, const float* __restrict__ offs,
    const float* __restrict__ mask, const float* __restrict__ Wkm,
    float* __restrict__ out) {
    __shared__ __align__(16) float a_lds[16 * KDIM];   // 36864 B; reused as outst
    __shared__ int    pi3[144 * 3];                    // lt, rb, dy
    __shared__ float4 pg4[144];

    int blk = blockIdx.x;
    int b  = blk & 7;                  // XCD swizzle: one batch per XCD
    int rem = blk >> 3;
    int h  = rem >> 3;
    int w0 = (rem & 7) * 16;
    int tid = threadIdx.x;

    // phase 1: sampling coords for 16 pos x 9 pts (proven math)
    if (tid < 144) {
        int e = tid;
        int pos = e / 9, n = e - pos * 9;
        int w = w0 + pos;
        int idx = ((b * 128 + h) * 128 + w);
        float ox = offs[idx * 18 + n];
        float oy = offs[idx * 18 + 9 + n];
        float mv = mask[idx * 9 + n];
        float px = ox + (float)(h + n / 3);
        float py = oy + (float)(w + n % 3);
        float flx = floorf(px), fly = floorf(py);
        float qltx = fminf(fmaxf(flx, 0.f), 129.f);
        float qlty = fminf(fmaxf(fly, 0.f), 129.f);
        float qrbx = fminf(fmaxf(flx + 1.f, 0.f), 129.f);
        float qrby = fminf(fmaxf(fly + 1.f, 0.f), 129.f);
        float pxc = fminf(fmaxf(px, 0.f), 129.f);
        float pyc = fminf(fmaxf(py, 0.f), 129.f);
        float glt = (1.f + qltx - pxc) * (1.f + qlty - pyc);
        float grb = (1.f - qrbx + pxc) * (1.f - qrby + pyc);
        float glb = (1.f + qltx - pxc) * (1.f - qrby + pyc);
        float grt = (1.f - qrbx + pxc) * (1.f + qlty - pyc);
        int ix_lt = (int)qltx, iy_lt = (int)qlty, ix_rb = (int)qrbx, iy_rb = (int)qrby;
        pi3[e * 3 + 0] = (ix_lt * 130 + iy_lt) * 64;
        pi3[e * 3 + 1] = (ix_rb * 130 + iy_rb) * 64;
        pi3[e * 3 + 2] = (iy_rb - iy_lt) * 64;
        pg4[e] = make_float4(glt * mv, grb * mv, glb * mv, grt * mv);
    }
    __syncthreads();

    // phase 2: gather+blend, a_lds[pos][k' = n*64 + ci] in fp32 (proven pattern)
    {
        const float* xb = x_t + (size_t)b * 130 * 130 * 64;
        int ci = tid & 63;
        for (int it = 0; it < 36; ++it) {
            int point = (tid >> 6) + it * 4;
            int pos = (point * 456) >> 12;          // point/9, exact for point<288
            int n = point - pos * 9;
            int lt = pi3[point * 3 + 0];
            int rb = pi3[point * 3 + 1];
            int dy = pi3[point * 3 + 2];
            float4 g = pg4[point];
            float v = g.x * xb[lt + ci] + g.y * xb[rb + ci] +
                      g.z * xb[lt + dy + ci] + g.w * xb[rb - dy + ci];
            a_lds[pos * KDIM + n * 64 + ci] = v;
        }
    }
    __syncthreads();

    // phase 3: co-banded pipelined dot.
    int cl = tid & 31;                 // co within band
    int ph = (tid >> 5) & 1;           // pos half
    int wv = tid >> 6;
    int co = wv * 32 + cl;
    int p0 = ph * 8;
    const float* W0 = Wkm + co;
    float acc[8] = {0.f, 0.f, 0.f, 0.f, 0.f, 0.f, 0.f, 0.f};
    // prefetch weights for k4 = 0
    float c0 = W0[0], c1 = W0[128], c2 = W0[256], c3 = W0[384];
    #pragma unroll 2
    for (int k4 = 0; k4 < 144; ++k4) {
        // prefetch next iteration (last iter over-reads 2KB into offs: benign)
        const float* Wn = W0 + (k4 + 1) * 512;
        float n0 = Wn[0], n1 = Wn[128], n2 = Wn[256], n3 = Wn[384];
        int kk = k4 * 4;
        #pragma unroll
        for (int p = 0; p < 8; ++p) {
            float4 a = *(const float4*)&a_lds[(p0 + p) * KDIM + kk];   // broadcast
            acc[p] += a.x * c0 + a.y * c1 + a.z * c2 + a.w * c3;
        }
        c0 = n0; c1 = n1; c2 = n2; c3 = n3;
    }
    __syncthreads();   // all a_lds reads done before aliasing overwrite

    // epilogue: stage via LDS, then coalesced global stores (proven path)
    float* outst = a_lds;                    // [128 co][17]
    #pragma unroll
    for (int p = 0; p < 8; ++p)
        outst[co * 17 + p0 + p] = acc[p];
    __syncthreads();
    for (int e = tid; e < 2048; e += 256) {
        int co2 = e >> 4, wl = e & 15;
        out[((size_t)(b * 128 + co2) * 16384) + h * 128 + w0 + wl] = outst[co2 * 17 + wl];
    }
}

// ---------------- BN stats: one block per (b, co) ----------------
__global__ __launch_bounds__(256) void k_stats(
    const float* __restrict__ out, float* __restrict__ partial) {
    __shared__ float s1[256], s2[256];
    int blk = blockIdx.x;
    const float4* p = (const float4*)(out + (size_t)blk * 16384);
    float a1 = 0.f, a2 = 0.f;
    for (int i = threadIdx.x; i < 4096; i += 256) {
        float4 v = p[i];
        a1 += v.x + v.y + v.z + v.w;
        a2 += v.x * v.x + v.y * v.y + v.z * v.z + v.w * v.w;
    }
    s1[threadIdx.x] = a1; s2[threadIdx.x] = a2;
    __syncthreads();
    for (int s = 128; s > 0; s >>= 1) {
        if (threadIdx.x < (unsigned)s) {
            s1[threadIdx.x] += s1[threadIdx.x + s];
            s2[threadIdx.x] += s2[threadIdx.x + s];
        }
        __syncthreads();
    }
    if (threadIdx.x == 0) { partial[blk] = s1[0]; partial[1024 + blk] = s2[0]; }
}

__global__ void k_finalize(const float* __restrict__ partial, const float* __restrict__ gamma,
                           const float* __restrict__ beta, float* __restrict__ sb) {
    int c = threadIdx.x;
    if (c < 128) {
        float s1 = 0.f, s2 = 0.f;
        for (int b = 0; b < 8; ++b) {
            s1 += partial[b * 128 + c];
            s2 += partial[1024 + b * 128 + c];
        }
        const float M = 131072.f;
        float mean = s1 / M;
        float var = fmaxf(s2 / M - mean * mean, 0.f);
        float sc = gamma[c] * rsqrtf(var + 1e-5f);
        sb[c] = sc;
        sb[128 + c] = beta[c] - mean * sc;
    }
}

__global__ void k_bnrelu(float* __restrict__ out, const float* __restrict__ sb) {
    int i = blockIdx.x * 256 + threadIdx.x;
    int c = (i >> 12) & 127;
    float4 v = ((float4*)out)[i];
    float sc = sb[c], bi = sb[128 + c];
    v.x = fmaxf(v.x * sc + bi, 0.f);
    v.y = fmaxf(v.y * sc + bi, 0.f);
    v.z = fmaxf(v.z * sc + bi, 0.f);
    v.w = fmaxf(v.w * sc + bi, 0.f);
    ((float4*)out)[i] = v;
}

extern "C" void kernel_launch(void* const* d_in, const int* in_sizes, int n_in,
                              void* d_out, int out_size, void* d_ws, size_t ws_size,
                              hipStream_t stream) {
    const float* x     = (const float*)d_in[0];
    const float* Wp    = (const float*)d_in[1];
    const float* bp    = (const float*)d_in[2];
    const float* Wm    = (const float*)d_in[3];
    const float* bm    = (const float*)d_in[4];
    const float* Wc    = (const float*)d_in[5];
    const float* gamma = (const float*)d_in[6];
    const float* beta  = (const float*)d_in[7];
    float* out = (float*)d_out;
    float* ws  = (float*)d_ws;

    // ws layout (floats)
    float* x_t     = ws;                         // 8,652,800
    float* Wkm     = x_t + 8652800;              // 73,728 (576*128 fp32, k-major)
    float* offs    = Wkm + 73728;                // 2,359,296 (absorbs benign over-read)
    float* mask    = offs + 2359296;             // 1,179,648
    float* partial = mask + 1179648;             // 2048
    float* sb      = partial + 2048;             // 256

    k_zero<<<8450, 256, 0, stream>>>((float4*)x_t, 2163200);
    k_pad_transpose<<<1024, 256, 0, stream>>>(x, x_t);
    k_wct<<<288, 256, 0, stream>>>(Wc, Wkm);
    k_offmask<<<2048, 256, 0, stream>>>(x_t, Wp, bp, Wm, bm, offs, mask);
    k_main<<<8192, 256, 0, stream>>>(x_t, offs, mask, Wkm, out);
    k_stats<<<1024, 256, 0, stream>>>(out, partial);
    k_finalize<<<1, 128, 0, stream>>>(partial, gamma, beta, sb);
    k_bnrelu<<<16384, 256, 0, stream>>>(out, sb);
}

// Round 15
// 613.923 us; speedup vs baseline: 1.3551x; 1.1785x over previous
//
#include <hip/hip_runtime.h>
#include <math.h>

// Problem constants: B=8, Cin=64, Cout=128, H=W=128, KS=3, N=9, K=576
#define KDIM 576

typedef float f32x2 __attribute__((ext_vector_type(2)));
typedef float f32x4v __attribute__((ext_vector_type(4)));

// ---------------- zero-fill x_t (border padding) ----------------
__global__ void k_zero(float4* __restrict__ p, int n4) {
    int i = blockIdx.x * 256 + threadIdx.x;
    if (i < n4) p[i] = make_float4(0.f, 0.f, 0.f, 0.f);
}

// ---------------- pad + NCHW->NHWC transpose ----------------
__global__ __launch_bounds__(256) void k_pad_transpose(
    const float* __restrict__ x, float* __restrict__ x_t) {
    __shared__ float lds[128 * 65];
    int b = blockIdx.x >> 7;
    int h = blockIdx.x & 127;
    for (int e = threadIdx.x; e < 64 * 128; e += 256) {
        int ci = e >> 7, w = e & 127;
        lds[w * 65 + ci] = x[((b * 64 + ci) * 128 + h) * 128 + w];
    }
    __syncthreads();
    for (int e = threadIdx.x; e < 128 * 64; e += 256) {
        int w = e >> 6, ci = e & 63;
        x_t[((b * 130 + h + 1) * 130 + (w + 1)) * 64 + ci] = lds[w * 65 + ci];
    }
}

// ---------------- W_conv -> k4-blocked: Wp4[(k4*128 + co)*4 + j] = Wc[co][k'=k4*4+j] ----------------
// (k' = n*64 + ci permutation, matching a_lds layout)
__global__ void k_wct(const float* __restrict__ Wc, float* __restrict__ Wp4) {
    int e = blockIdx.x * 256 + threadIdx.x;
    if (e >= 128 * KDIM) return;
    int j = e & 3, co = (e >> 2) & 127, k4 = e >> 9;
    int kp = k4 * 4 + j;
    int n = kp >> 6, ci = kp & 63;
    Wp4[e] = Wc[co * KDIM + ci * 9 + n];
}

// ---------------- offset + mask 3x3 convs: wave-uniform 7-oc blocking (R13-proven) ----------------
__global__ __launch_bounds__(256) void k_offmask(
    const float* __restrict__ x_t, const float* __restrict__ Wp, const float* __restrict__ bp,
    const float* __restrict__ Wm, const float* __restrict__ bm,
    float* __restrict__ offs, float* __restrict__ mask) {
    __shared__ float lds[198 * 65];
    int t = blockIdx.x;
    int wt = t & 1, h = (t >> 1) & 127, b = t >> 8;
    int w0 = wt * 64;
    for (int e = threadIdx.x; e < 198 * 64; e += 256) {
        int chunk = e >> 6, ci = e & 63;
        int row = chunk / 66, col = chunk % 66;
        lds[chunk * 65 + ci] = x_t[((b * 130 + h + row) * 130 + (w0 + col)) * 64 + ci];
    }
    __syncthreads();

    int wl = threadIdx.x & 63;
    int q  = __builtin_amdgcn_readfirstlane(threadIdx.x >> 6);
    int oc0 = q * 7;
    int noc = (q == 3) ? 6 : 7;

    const float* wrows[7];
    #pragma unroll
    for (int j = 0; j < 7; ++j) {
        int oc = oc0 + j;
        wrows[j] = (oc < 18) ? (Wp + oc * KDIM) : (Wm + (oc - 18) * KDIM);
    }

    float acc[7] = {0.f, 0.f, 0.f, 0.f, 0.f, 0.f, 0.f};
    for (int ci = 0; ci < 64; ++ci) {
        #pragma unroll
        for (int kx = 0; kx < 3; ++kx) {
            float x0 = lds[(kx * 66 + wl + 0) * 65 + ci];
            float x1 = lds[(kx * 66 + wl + 1) * 65 + ci];
            float x2 = lds[(kx * 66 + wl + 2) * 65 + ci];
            #pragma unroll
            for (int j = 0; j < 7; ++j) {
                if (j < noc) {
                    const float* wk = wrows[j] + ci * 9 + kx * 3;
                    acc[j] += x0 * wk[0] + x1 * wk[1] + x2 * wk[2];
                }
            }
        }
    }

    int idx = ((b * 128 + h) * 128 + (w0 + wl));
    #pragma unroll
    for (int j = 0; j < 7; ++j) {
        if (j < noc) {
            int oc = oc0 + j;
            if (oc < 18) {
                offs[idx * 18 + oc] = acc[j] + bp[oc];
            } else {
                float v = acc[j] + bm[oc - 18];
                mask[idx * 9 + (oc - 18)] = 1.f / (1.f + __expf(-v));
            }
        }
    }
}

// ---------------- main: deformable sample -> packed-math VALU dot ----------------
// block = 16 positions; grid = 8192, XCD-pinned; 4 blocks/CU (LDS 40896 B).
// Phase 3: wave = pos-group of 4 (wave-uniform broadcast ds_reads), lane = co,
// thread = 2 co x 4 pos. Weights from Wp4: one coalesced dwordx4 per co per k4.
// Inner MACs as float2 elementwise-fma -> v_pk_fma_f32 (2 MACs/instr).
__global__ __launch_bounds__(256, 4) void k_main(
    const float* __restrict__ x_t, const float* __restrict__ offs,
    const float* __restrict__ mask, const float* __restrict__ Wp4,
    float* __restrict__ out) {
    __shared__ __align__(16) float a_lds[16 * KDIM];   // 36864 B; reused as outst
    __shared__ int    pi3[144 * 3];                    // lt, rb, dy
    __shared__ float4 pg4[144];

    int blk = blockIdx.x;
    int b  = blk & 7;                  // XCD swizzle: one batch per XCD
    int rem = blk >> 3;
    int h  = rem >> 3;
    int w0 = (rem & 7) * 16;
    int tid = threadIdx.x;

    // phase 1: sampling coords for 16 pos x 9 pts (proven math)
    if (tid < 144) {
        int e = tid;
        int pos = e / 9, n = e - pos * 9;
        int w = w0 + pos;
        int idx = ((b * 128 + h) * 128 + w);
        float ox = offs[idx * 18 + n];
        float oy = offs[idx * 18 + 9 + n];
        float mv = mask[idx * 9 + n];
        float px = ox + (float)(h + n / 3);
        float py = oy + (float)(w + n % 3);
        float flx = floorf(px), fly = floorf(py);
        float qltx = fminf(fmaxf(flx, 0.f), 129.f);
        float qlty = fminf(fmaxf(fly, 0.f), 129.f);
        float qrbx = fminf(fmaxf(flx + 1.f, 0.f), 129.f);
        float qrby = fminf(fmaxf(fly + 1.f, 0.f), 129.f);
        float pxc = fminf(fmaxf(px, 0.f), 129.f);
        float pyc = fminf(fmaxf(py, 0.f), 129.f);
        float glt = (1.f + qltx - pxc) * (1.f + qlty - pyc);
        float grb = (1.f - qrbx + pxc) * (1.f - qrby + pyc);
        float glb = (1.f + qltx - pxc) * (1.f - qrby + pyc);
        float grt = (1.f - qrbx + pxc) * (1.f + qlty - pyc);
        int ix_lt = (int)qltx, iy_lt = (int)qlty, ix_rb = (int)qrbx, iy_rb = (int)qrby;
        pi3[e * 3 + 0] = (ix_lt * 130 + iy_lt) * 64;
        pi3[e * 3 + 1] = (ix_rb * 130 + iy_rb) * 64;
        pi3[e * 3 + 2] = (iy_rb - iy_lt) * 64;
        pg4[e] = make_float4(glt * mv, grb * mv, glb * mv, grt * mv);
    }
    __syncthreads();

    // phase 2: gather+blend, a_lds[pos][k' = n*64 + ci] in fp32 (proven pattern)
    {
        const float* xb = x_t + (size_t)b * 130 * 130 * 64;
        int ci = tid & 63;
        for (int it = 0; it < 36; ++it) {
            int point = (tid >> 6) + it * 4;
            int pos = (point * 456) >> 12;          // point/9, exact for point<288
            int n = point - pos * 9;
            int lt = pi3[point * 3 + 0];
            int rb = pi3[point * 3 + 1];
            int dy = pi3[point * 3 + 2];
            float4 g = pg4[point];
            float v = g.x * xb[lt + ci] + g.y * xb[rb + ci] +
                      g.z * xb[lt + dy + ci] + g.w * xb[rb - dy + ci];
            a_lds[pos * KDIM + n * 64 + ci] = v;
        }
    }
    __syncthreads();

    // phase 3: packed-math dot. lane = co (+64), wave pg = pos group of 4.
    int lane = tid & 63, pg = tid >> 6;
    const f32x4v* W4 = (const f32x4v*)Wp4;           // [(k4*128 + co)]
    f32x2 s0[4], s1[4];
    #pragma unroll
    for (int p = 0; p < 4; ++p) { s0[p] = (f32x2){0.f, 0.f}; s1[p] = (f32x2){0.f, 0.f}; }

    // prefetch k4 = 0 weights
    f32x4v wc0 = W4[lane];
    f32x4v wc1 = W4[lane + 64];
    #pragma unroll 2
    for (int k4 = 0; k4 < 144; ++k4) {
        // prefetch next (last iter over-reads 2KB into offs: benign)
        f32x4v wn0 = W4[(k4 + 1) * 128 + lane];
        f32x4v wn1 = W4[(k4 + 1) * 128 + lane + 64];
        f32x2 w0lo = __builtin_shufflevector(wc0, wc0, 0, 1);
        f32x2 w0hi = __builtin_shufflevector(wc0, wc0, 2, 3);
        f32x2 w1lo = __builtin_shufflevector(wc1, wc1, 0, 1);
        f32x2 w1hi = __builtin_shufflevector(wc1, wc1, 2, 3);
        int kk = k4 * 4;
        #pragma unroll
        for (int p = 0; p < 4; ++p) {
            f32x4v a = *(const f32x4v*)&a_lds[(pg * 4 + p) * KDIM + kk];   // broadcast
            f32x2 alo = __builtin_shufflevector(a, a, 0, 1);
            f32x2 ahi = __builtin_shufflevector(a, a, 2, 3);
            s0[p] = __builtin_elementwise_fma(alo, w0lo, s0[p]);
            s0[p] = __builtin_elementwise_fma(ahi, w0hi, s0[p]);
            s1[p] = __builtin_elementwise_fma(alo, w1lo, s1[p]);
            s1[p] = __builtin_elementwise_fma(ahi, w1hi, s1[p]);
        }
        wc0 = wn0; wc1 = wn1;
    }
    __syncthreads();   // all a_lds reads done before aliasing overwrite

    // epilogue: stage via LDS, then coalesced global stores (proven path)
    float* outst = a_lds;                    // [128 co][17]
    #pragma unroll
    for (int p = 0; p < 4; ++p) {
        outst[lane * 17 + pg * 4 + p]        = s0[p].x + s0[p].y;
        outst[(lane + 64) * 17 + pg * 4 + p] = s1[p].x + s1[p].y;
    }
    __syncthreads();
    for (int e = tid; e < 2048; e += 256) {
        int co2 = e >> 4, wl = e & 15;
        out[((size_t)(b * 128 + co2) * 16384) + h * 128 + w0 + wl] = outst[co2 * 17 + wl];
    }
}

// ---------------- BN stats: one block per (b, co) ----------------
__global__ __launch_bounds__(256) void k_stats(
    const float* __restrict__ out, float* __restrict__ partial) {
    __shared__ float s1[256], s2[256];
    int blk = blockIdx.x;
    const float4* p = (const float4*)(out + (size_t)blk * 16384);
    float a1 = 0.f, a2 = 0.f;
    for (int i = threadIdx.x; i < 4096; i += 256) {
        float4 v = p[i];
        a1 += v.x + v.y + v.z + v.w;
        a2 += v.x * v.x + v.y * v.y + v.z * v.z + v.w * v.w;
    }
    s1[threadIdx.x] = a1; s2[threadIdx.x] = a2;
    __syncthreads();
    for (int s = 128; s > 0; s >>= 1) {
        if (threadIdx.x < (unsigned)s) {
            s1[threadIdx.x] += s1[threadIdx.x + s];
            s2[threadIdx.x] += s2[threadIdx.x + s];
        }
        __syncthreads();
    }
    if (threadIdx.x == 0) { partial[blk] = s1[0]; partial[1024 + blk] = s2[0]; }
}

__global__ void k_finalize(const float* __restrict__ partial, const float* __restrict__ gamma,
                           const float* __restrict__ beta, float* __restrict__ sb) {
    int c = threadIdx.x;
    if (c < 128) {
        float s1 = 0.f, s2 = 0.f;
        for (int b = 0; b < 8; ++b) {
            s1 += partial[b * 128 + c];
            s2 += partial[1024 + b * 128 + c];
        }
        const float M = 131072.f;
        float mean = s1 / M;
        float var = fmaxf(s2 / M - mean * mean, 0.f);
        float sc = gamma[c] * rsqrtf(var + 1e-5f);
        sb[c] = sc;
        sb[128 + c] = beta[c] - mean * sc;
    }
}

__global__ void k_bnrelu(float* __restrict__ out, const float* __restrict__ sb) {
    int i = blockIdx.x * 256 + threadIdx.x;
    int c = (i >> 12) & 127;
    float4 v = ((float4*)out)[i];
    float sc = sb[c], bi = sb[128 + c];
    v.x = fmaxf(v.x * sc + bi, 0.f);
    v.y = fmaxf(v.y * sc + bi, 0.f);
    v.z = fmaxf(v.z * sc + bi, 0.f);
    v.w = fmaxf(v.w * sc + bi, 0.f);
    ((float4*)out)[i] = v;
}

extern "C" void kernel_launch(void* const* d_in, const int* in_sizes, int n_in,
                              void* d_out, int out_size, void* d_ws, size_t ws_size,
                              hipStream_t stream) {
    const float* x     = (const float*)d_in[0];
    const float* Wp    = (const float*)d_in[1];
    const float* bp    = (const float*)d_in[2];
    const float* Wm    = (const float*)d_in[3];
    const float* bm    = (const float*)d_in[4];
    const float* Wc    = (const float*)d_in[5];
    const float* gamma = (const float*)d_in[6];
    const float* beta  = (const float*)d_in[7];
    float* out = (float*)d_out;
    float* ws  = (float*)d_ws;

    // ws layout (floats)
    float* x_t     = ws;                         // 8,652,800
    float* Wp4     = x_t + 8652800;              // 73,728 (k4-blocked fp32)
    float* offs    = Wp4 + 73728;                // 2,359,296 (absorbs benign over-read)
    float* mask    = offs + 2359296;             // 1,179,648
    float* partial = mask + 1179648;             // 2048
    float* sb      = partial + 2048;             // 256

    k_zero<<<8450, 256, 0, stream>>>((float4*)x_t, 2163200);
    k_pad_transpose<<<1024, 256, 0, stream>>>(x, x_t);
    k_wct<<<288, 256, 0, stream>>>(Wc, Wp4);
    k_offmask<<<2048, 256, 0, stream>>>(x_t, Wp, bp, Wm, bm, offs, mask);
    k_main<<<8192, 256, 0, stream>>>(x_t, offs, mask, Wp4, out);
    k_stats<<<1024, 256, 0, stream>>>(out, partial);
    k_finalize<<<1, 128, 0, stream>>>(partial, gamma, beta, sb);
    k_bnrelu<<<16384, 256, 0, stream>>>(out, sb);
}

// Round 16
// 489.885 us; speedup vs baseline: 1.6983x; 1.2532x over previous
//
#include <hip/hip_runtime.h>
#include <math.h>

// Problem constants: B=8, Cin=64, Cout=128, H=W=128, KS=3, N=9, K=576
#define KDIM 576
#define AHSTRIDE 584   // f16 per position row (576 + 8 pad), 1168 B, 16B-aligned

typedef _Float16 h2 __attribute__((ext_vector_type(2)));

// ---------------- zero-fill x_t (border padding) ----------------
__global__ void k_zero(float4* __restrict__ p, int n4) {
    int i = blockIdx.x * 256 + threadIdx.x;
    if (i < n4) p[i] = make_float4(0.f, 0.f, 0.f, 0.f);
}

// ---------------- pad + NCHW->NHWC transpose ----------------
__global__ __launch_bounds__(256) void k_pad_transpose(
    const float* __restrict__ x, float* __restrict__ x_t) {
    __shared__ float lds[128 * 65];
    int b = blockIdx.x >> 7;
    int h = blockIdx.x & 127;
    for (int e = threadIdx.x; e < 64 * 128; e += 256) {
        int ci = e >> 7, w = e & 127;
        lds[w * 65 + ci] = x[((b * 64 + ci) * 128 + h) * 128 + w];
    }
    __syncthreads();
    for (int e = threadIdx.x; e < 128 * 64; e += 256) {
        int w = e >> 6, ci = e & 63;
        x_t[((b * 130 + h + 1) * 130 + (w + 1)) * 64 + ci] = lds[w * 65 + ci];
    }
}

// ---------------- W_conv -> f16, k8-blocked: Wh[(k8*128+co)*8 + j] = Wc[co][k'=k8*8+j] ----------------
// (k' = n*64 + ci permutation, matching a_lds layout)
__global__ void k_wct(const float* __restrict__ Wc, _Float16* __restrict__ Wh) {
    int e = blockIdx.x * 256 + threadIdx.x;
    if (e >= 72 * 128 * 8) return;
    int j = e & 7, idx = e >> 3;
    int co = idx & 127, k8 = idx >> 7;
    int kp = k8 * 8 + j;
    int n = kp >> 6, ci = kp & 63;
    Wh[e] = (_Float16)Wc[co * KDIM + ci * 9 + n];
}

// ---------------- offset + mask 3x3 convs: wave-uniform 7-oc blocking (R13-proven) ----------------
__global__ __launch_bounds__(256) void k_offmask(
    const float* __restrict__ x_t, const float* __restrict__ Wp, const float* __restrict__ bp,
    const float* __restrict__ Wm, const float* __restrict__ bm,
    float* __restrict__ offs, float* __restrict__ mask) {
    __shared__ float lds[198 * 65];
    int t = blockIdx.x;
    int wt = t & 1, h = (t >> 1) & 127, b = t >> 8;
    int w0 = wt * 64;
    for (int e = threadIdx.x; e < 198 * 64; e += 256) {
        int chunk = e >> 6, ci = e & 63;
        int row = chunk / 66, col = chunk % 66;
        lds[chunk * 65 + ci] = x_t[((b * 130 + h + row) * 130 + (w0 + col)) * 64 + ci];
    }
    __syncthreads();

    int wl = threadIdx.x & 63;
    int q  = __builtin_amdgcn_readfirstlane(threadIdx.x >> 6);
    int oc0 = q * 7;
    int noc = (q == 3) ? 6 : 7;

    const float* wrows[7];
    #pragma unroll
    for (int j = 0; j < 7; ++j) {
        int oc = oc0 + j;
        wrows[j] = (oc < 18) ? (Wp + oc * KDIM) : (Wm + (oc - 18) * KDIM);
    }

    float acc[7] = {0.f, 0.f, 0.f, 0.f, 0.f, 0.f, 0.f};
    for (int ci = 0; ci < 64; ++ci) {
        #pragma unroll
        for (int kx = 0; kx < 3; ++kx) {
            float x0 = lds[(kx * 66 + wl + 0) * 65 + ci];
            float x1 = lds[(kx * 66 + wl + 1) * 65 + ci];
            float x2 = lds[(kx * 66 + wl + 2) * 65 + ci];
            #pragma unroll
            for (int j = 0; j < 7; ++j) {
                if (j < noc) {
                    const float* wk = wrows[j] + ci * 9 + kx * 3;
                    acc[j] += x0 * wk[0] + x1 * wk[1] + x2 * wk[2];
                }
            }
        }
    }

    int idx = ((b * 128 + h) * 128 + (w0 + wl));
    #pragma unroll
    for (int j = 0; j < 7; ++j) {
        if (j < noc) {
            int oc = oc0 + j;
            if (oc < 18) {
                offs[idx * 18 + oc] = acc[j] + bp[oc];
            } else {
                float v = acc[j] + bm[oc - 18];
                mask[idx * 9 + (oc - 18)] = 1.f / (1.f + __expf(-v));
            }
        }
    }
}

// ---------------- main: deformable sample -> f16 v_dot2 dot ----------------
// block = 16 positions; grid = 8192, XCD-pinned; LDS 22.7 KB -> ~6 blocks/CU.
// Phase 3: wave = pos-group of 4 (broadcast ds_reads), lane = co (+64);
// thread = 2 co x 4 pos. A and W in f16; v_dot2_f32_f16 = 2 MACs/instr, fp32 acc.
// Each b128 A-read now delivers 8 k-values (halves LDS-pipe traffic vs fp32).
__global__ __launch_bounds__(256, 6) void k_main(
    const float* __restrict__ x_t, const float* __restrict__ offs,
    const float* __restrict__ mask, const _Float16* __restrict__ Wh,
    float* __restrict__ out) {
    __shared__ __align__(16) _Float16 a_lds[16 * AHSTRIDE];   // 18688 B; reused as outst
    __shared__ int    pi3[144 * 3];                           // lt, rb, dy
    __shared__ float4 pg4[144];

    int blk = blockIdx.x;
    int b  = blk & 7;                  // XCD swizzle: one batch per XCD
    int rem = blk >> 3;
    int h  = rem >> 3;
    int w0 = (rem & 7) * 16;
    int tid = threadIdx.x;

    // phase 1: sampling coords for 16 pos x 9 pts (proven math)
    if (tid < 144) {
        int e = tid;
        int pos = e / 9, n = e - pos * 9;
        int w = w0 + pos;
        int idx = ((b * 128 + h) * 128 + w);
        float ox = offs[idx * 18 + n];
        float oy = offs[idx * 18 + 9 + n];
        float mv = mask[idx * 9 + n];
        float px = ox + (float)(h + n / 3);
        float py = oy + (float)(w + n % 3);
        float flx = floorf(px), fly = floorf(py);
        float qltx = fminf(fmaxf(flx, 0.f), 129.f);
        float qlty = fminf(fmaxf(fly, 0.f), 129.f);
        float qrbx = fminf(fmaxf(flx + 1.f, 0.f), 129.f);
        float qrby = fminf(fmaxf(fly + 1.f, 0.f), 129.f);
        float pxc = fminf(fmaxf(px, 0.f), 129.f);
        float pyc = fminf(fmaxf(py, 0.f), 129.f);
        float glt = (1.f + qltx - pxc) * (1.f + qlty - pyc);
        float grb = (1.f - qrbx + pxc) * (1.f - qrby + pyc);
        float glb = (1.f + qltx - pxc) * (1.f - qrby + pyc);
        float grt = (1.f - qrbx + pxc) * (1.f + qlty - pyc);
        int ix_lt = (int)qltx, iy_lt = (int)qlty, ix_rb = (int)qrbx, iy_rb = (int)qrby;
        pi3[e * 3 + 0] = (ix_lt * 130 + iy_lt) * 64;
        pi3[e * 3 + 1] = (ix_rb * 130 + iy_rb) * 64;
        pi3[e * 3 + 2] = (iy_rb - iy_lt) * 64;
        pg4[e] = make_float4(glt * mv, grb * mv, glb * mv, grt * mv);
    }
    __syncthreads();

    // phase 2: gather+blend, a_lds[pos][k' = n*64 + ci] in f16 (proven pattern)
    {
        const float* xb = x_t + (size_t)b * 130 * 130 * 64;
        int ci = tid & 63;
        for (int it = 0; it < 36; ++it) {
            int point = (tid >> 6) + it * 4;
            int pos = (point * 456) >> 12;          // point/9, exact for point<288
            int n = point - pos * 9;
            int lt = pi3[point * 3 + 0];
            int rb = pi3[point * 3 + 1];
            int dy = pi3[point * 3 + 2];
            float4 g = pg4[point];
            float v = g.x * xb[lt + ci] + g.y * xb[rb + ci] +
                      g.z * xb[lt + dy + ci] + g.w * xb[rb - dy + ci];
            a_lds[pos * AHSTRIDE + n * 64 + ci] = (_Float16)v;
        }
    }
    __syncthreads();

    // phase 3: f16 dot2. lane = co (+64), wave pg = pos group of 4.
    int lane = tid & 63, pg = tid >> 6;
    const uint4* W4 = (const uint4*)Wh;              // [(k8*128 + co)] = 8 f16
    float acc0[4] = {0.f, 0.f, 0.f, 0.f};
    float acc1[4] = {0.f, 0.f, 0.f, 0.f};

    // prefetch k8 = 0 weights
    uint4 wc0 = W4[lane];
    uint4 wc1 = W4[lane + 64];
    #pragma unroll 2
    for (int k8 = 0; k8 < 72; ++k8) {
        // prefetch next (k8=71 reads row 72 -> still inside the Wh region: benign pad)
        uint4 wn0 = W4[(k8 + 1) * 128 + lane];
        uint4 wn1 = W4[(k8 + 1) * 128 + lane + 64];
        h2 w00 = __builtin_bit_cast(h2, wc0.x), w01 = __builtin_bit_cast(h2, wc0.y),
           w02 = __builtin_bit_cast(h2, wc0.z), w03 = __builtin_bit_cast(h2, wc0.w);
        h2 w10 = __builtin_bit_cast(h2, wc1.x), w11 = __builtin_bit_cast(h2, wc1.y),
           w12 = __builtin_bit_cast(h2, wc1.z), w13 = __builtin_bit_cast(h2, wc1.w);
        #pragma unroll
        for (int p = 0; p < 4; ++p) {
            uint4 a = *(const uint4*)&a_lds[(pg * 4 + p) * AHSTRIDE + k8 * 8];  // broadcast
            h2 a0 = __builtin_bit_cast(h2, a.x), a1 = __builtin_bit_cast(h2, a.y),
               a2 = __builtin_bit_cast(h2, a.z), a3 = __builtin_bit_cast(h2, a.w);
            acc0[p] = __builtin_amdgcn_fdot2(a0, w00, acc0[p], false);
            acc0[p] = __builtin_amdgcn_fdot2(a1, w01, acc0[p], false);
            acc0[p] = __builtin_amdgcn_fdot2(a2, w02, acc0[p], false);
            acc0[p] = __builtin_amdgcn_fdot2(a3, w03, acc0[p], false);
            acc1[p] = __builtin_amdgcn_fdot2(a0, w10, acc1[p], false);
            acc1[p] = __builtin_amdgcn_fdot2(a1, w11, acc1[p], false);
            acc1[p] = __builtin_amdgcn_fdot2(a2, w12, acc1[p], false);
            acc1[p] = __builtin_amdgcn_fdot2(a3, w13, acc1[p], false);
        }
        wc0 = wn0; wc1 = wn1;
    }
    __syncthreads();   // all a_lds reads done before aliasing overwrite

    // epilogue: stage via LDS, then coalesced global stores (proven path)
    float* outst = (float*)a_lds;                    // [128 co][17]
    #pragma unroll
    for (int p = 0; p < 4; ++p) {
        outst[lane * 17 + pg * 4 + p]        = acc0[p];
        outst[(lane + 64) * 17 + pg * 4 + p] = acc1[p];
    }
    __syncthreads();
    for (int e = tid; e < 2048; e += 256) {
        int co2 = e >> 4, wl = e & 15;
        out[((size_t)(b * 128 + co2) * 16384) + h * 128 + w0 + wl] = outst[co2 * 17 + wl];
    }
}

// ---------------- BN stats: one block per (b, co) ----------------
__global__ __launch_bounds__(256) void k_stats(
    const float* __restrict__ out, float* __restrict__ partial) {
    __shared__ float s1[256], s2[256];
    int blk = blockIdx.x;
    const float4* p = (const float4*)(out + (size_t)blk * 16384);
    float a1 = 0.f, a2 = 0.f;
    for (int i = threadIdx.x; i < 4096; i += 256) {
        float4 v = p[i];
        a1 += v.x + v.y + v.z + v.w;
        a2 += v.x * v.x + v.y * v.y + v.z * v.z + v.w * v.w;
    }
    s1[threadIdx.x] = a1; s2[threadIdx.x] = a2;
    __syncthreads();
    for (int s = 128; s > 0; s >>= 1) {
        if (threadIdx.x < (unsigned)s) {
            s1[threadIdx.x] += s1[threadIdx.x + s];
            s2[threadIdx.x] += s2[threadIdx.x + s];
        }
        __syncthreads();
    }
    if (threadIdx.x == 0) { partial[blk] = s1[0]; partial[1024 + blk] = s2[0]; }
}

__global__ void k_finalize(const float* __restrict__ partial, const float* __restrict__ gamma,
                           const float* __restrict__ beta, float* __restrict__ sb) {
    int c = threadIdx.x;
    if (c < 128) {
        float s1 = 0.f, s2 = 0.f;
        for (int b = 0; b < 8; ++b) {
            s1 += partial[b * 128 + c];
            s2 += partial[1024 + b * 128 + c];
        }
        const float M = 131072.f;
        float mean = s1 / M;
        float var = fmaxf(s2 / M - mean * mean, 0.f);
        float sc = gamma[c] * rsqrtf(var + 1e-5f);
        sb[c] = sc;
        sb[128 + c] = beta[c] - mean * sc;
    }
}

__global__ void k_bnrelu(float* __restrict__ out, const float* __restrict__ sb) {
    int i = blockIdx.x * 256 + threadIdx.x;
    int c = (i >> 12) & 127;
    float4 v = ((float4*)out)[i];
    float sc = sb[c], bi = sb[128 + c];
    v.x = fmaxf(v.x * sc + bi, 0.f);
    v.y = fmaxf(v.y * sc + bi, 0.f);
    v.z = fmaxf(v.z * sc + bi, 0.f);
    v.w = fmaxf(v.w * sc + bi, 0.f);
    ((float4*)out)[i] = v;
}

extern "C" void kernel_launch(void* const* d_in, const int* in_sizes, int n_in,
                              void* d_out, int out_size, void* d_ws, size_t ws_size,
                              hipStream_t stream) {
    const float* x     = (const float*)d_in[0];
    const float* Wp    = (const float*)d_in[1];
    const float* bp    = (const float*)d_in[2];
    const float* Wm    = (const float*)d_in[3];
    const float* bm    = (const float*)d_in[4];
    const float* Wc    = (const float*)d_in[5];
    const float* gamma = (const float*)d_in[6];
    const float* beta  = (const float*)d_in[7];
    float* out = (float*)d_out;
    float* ws  = (float*)d_ws;

    // ws layout (floats) — Wh occupies the first half of the old 73728-float slot
    float* x_t     = ws;                         // 8,652,800
    _Float16* Wh   = (_Float16*)(x_t + 8652800); // 73,728 f16 (region reserves 73,728 floats)
    float* offs    = x_t + 8652800 + 73728;      // 2,359,296
    float* mask    = offs + 2359296;             // 1,179,648
    float* partial = mask + 1179648;             // 2048
    float* sb      = partial + 2048;             // 256

    k_zero<<<8450, 256, 0, stream>>>((float4*)x_t, 2163200);
    k_pad_transpose<<<1024, 256, 0, stream>>>(x, x_t);
    k_wct<<<288, 256, 0, stream>>>(Wc, Wh);
    k_offmask<<<2048, 256, 0, stream>>>(x_t, Wp, bp, Wm, bm, offs, mask);
    k_main<<<8192, 256, 0, stream>>>(x_t, offs, mask, Wh, out);
    k_stats<<<1024, 256, 0, stream>>>(out, partial);
    k_finalize<<<1, 128, 0, stream>>>(partial, gamma, beta, sb);
    k_bnrelu<<<16384, 256, 0, stream>>>(out, sb);
}

// Round 17
// 367.921 us; speedup vs baseline: 2.2612x; 1.3315x over previous
//
#include <hip/hip_runtime.h>
#include <math.h>

// Problem constants: B=8, Cin=64, Cout=128, H=W=128, KS=3, N=9, K=576
#define KDIM 576
#define AHSTRIDE 584   // f16 per position row (576 + 8 pad), 1168 B, 16B-aligned

typedef _Float16 h2 __attribute__((ext_vector_type(2)));

// ---------------- zero-fill x_t (border padding) ----------------
__global__ void k_zero(float4* __restrict__ p, int n4) {
    int i = blockIdx.x * 256 + threadIdx.x;
    if (i < n4) p[i] = make_float4(0.f, 0.f, 0.f, 0.f);
}

// ---------------- pad + NCHW->NHWC transpose ----------------
__global__ __launch_bounds__(256) void k_pad_transpose(
    const float* __restrict__ x, float* __restrict__ x_t) {
    __shared__ float lds[128 * 65];
    int b = blockIdx.x >> 7;
    int h = blockIdx.x & 127;
    for (int e = threadIdx.x; e < 64 * 128; e += 256) {
        int ci = e >> 7, w = e & 127;
        lds[w * 65 + ci] = x[((b * 64 + ci) * 128 + h) * 128 + w];
    }
    __syncthreads();
    for (int e = threadIdx.x; e < 128 * 64; e += 256) {
        int w = e >> 6, ci = e & 63;
        x_t[((b * 130 + h + 1) * 130 + (w + 1)) * 64 + ci] = lds[w * 65 + ci];
    }
}

// ---------------- W_conv -> f16, k8-blocked: Wh[(k8*128+co)*8 + j] = Wc[co][k'=k8*8+j] ----------------
__global__ void k_wct(const float* __restrict__ Wc, _Float16* __restrict__ Wh) {
    int e = blockIdx.x * 256 + threadIdx.x;
    if (e >= 72 * 128 * 8) return;
    int j = e & 7, idx = e >> 3;
    int co = idx & 127, k8 = idx >> 7;
    int kp = k8 * 8 + j;
    int n = kp >> 6, ci = kp & 63;
    Wh[e] = (_Float16)Wc[co * KDIM + ci * 9 + n];
}

// ---------------- Wp/Wm -> f16, k8-blocked, 32-co padded (27 real) ----------------
// Wh27[(k8*32 + co)*8 + j] = W'[co][k'=k8*8+j]; rows k8=72 zero-padded for prefetch.
__global__ void k_wpm(const float* __restrict__ Wp, const float* __restrict__ Wm,
                      _Float16* __restrict__ Wh27) {
    int e = blockIdx.x * 256 + threadIdx.x;
    if (e >= 73 * 32 * 8) return;
    int j = e & 7, idx = e >> 3;
    int co = idx & 31, k8 = idx >> 5;
    float v = 0.f;
    if (k8 < 72 && co < 27) {
        int kp = k8 * 8 + j;
        int n = kp >> 6, ci = kp & 63;
        v = (co < 18) ? Wp[co * KDIM + ci * 9 + n] : Wm[(co - 18) * KDIM + ci * 9 + n];
    }
    Wh27[e] = (_Float16)v;
}

// ---------------- offset + mask convs: f16 fdot2, k_main-style ----------------
// block = 32 positions (one b,h, quarter-row); grid = 4096, XCD-pinned.
// Stage A (integer 3x3 neighborhood) in f16 LDS with k'=n*64+ci layout, then
// thread = 1 co (of 32, 27 real) x 4 pos; per k8: 1 uint4 weight + 4 a-reads + 16 fdot2.
__global__ __launch_bounds__(256) void k_offmask(
    const float* __restrict__ x_t, const _Float16* __restrict__ Wh27,
    const float* __restrict__ bp, const float* __restrict__ bm,
    float* __restrict__ offs, float* __restrict__ mask) {
    __shared__ __align__(16) _Float16 a_lds[32 * AHSTRIDE];   // 37376 B

    int blk = blockIdx.x;
    int b  = blk & 7;
    int rem = blk >> 3;
    int h  = rem >> 2;
    int w0 = (rem & 3) * 32;
    int tid = threadIdx.x;

    // stage: a_lds[pos][n*64+ci] = x_t[b][h+kx][w0+pos+ky][ci], n = kx*3+ky
    {
        const float* xb = x_t + (size_t)b * 130 * 130 * 64;
        int ci = tid & 63;
        for (int it = 0; it < 72; ++it) {
            int point = (tid >> 6) + it * 4;            // pos*9 + n, point < 288
            int pos = (point * 456) >> 12;
            int n = point - pos * 9;
            int kx = n / 3, ky = n - kx * 3;
            float v = xb[((h + kx) * 130 + (w0 + pos + ky)) * 64 + ci];
            a_lds[pos * AHSTRIDE + n * 64 + ci] = (_Float16)v;
        }
    }
    __syncthreads();

    // dot: co = tid&31 (27 real), wave wv covers 8 pos, ph picks the half
    int co = tid & 31;
    int ph = (tid >> 5) & 1;
    int wv = tid >> 6;
    int pbase = wv * 8 + ph * 4;
    const uint4* W4 = (const uint4*)Wh27;               // [(k8*32 + co)]
    float acc[4] = {0.f, 0.f, 0.f, 0.f};
    uint4 wc = W4[co];
    for (int k8 = 0; k8 < 72; ++k8) {
        uint4 wn = W4[(k8 + 1) * 32 + co];              // k8=71 reads zero pad row
        h2 w0h = __builtin_bit_cast(h2, wc.x), w1h = __builtin_bit_cast(h2, wc.y),
           w2h = __builtin_bit_cast(h2, wc.z), w3h = __builtin_bit_cast(h2, wc.w);
        #pragma unroll
        for (int p = 0; p < 4; ++p) {
            uint4 a = *(const uint4*)&a_lds[(pbase + p) * AHSTRIDE + k8 * 8];
            h2 a0 = __builtin_bit_cast(h2, a.x), a1 = __builtin_bit_cast(h2, a.y),
               a2 = __builtin_bit_cast(h2, a.z), a3 = __builtin_bit_cast(h2, a.w);
            acc[p] = __builtin_amdgcn_fdot2(a0, w0h, acc[p], false);
            acc[p] = __builtin_amdgcn_fdot2(a1, w1h, acc[p], false);
            acc[p] = __builtin_amdgcn_fdot2(a2, w2h, acc[p], false);
            acc[p] = __builtin_amdgcn_fdot2(a3, w3h, acc[p], false);
        }
        wc = wn;
    }

    // write: offs (co<18) with bias; mask (18<=co<27) with sigmoid
    if (co < 27) {
        #pragma unroll
        for (int p = 0; p < 4; ++p) {
            int w = w0 + pbase + p;
            int idx = ((b * 128 + h) * 128 + w);
            if (co < 18) {
                offs[idx * 18 + co] = acc[p] + bp[co];
            } else {
                float v = acc[p] + bm[co - 18];
                mask[idx * 9 + (co - 18)] = 1.f / (1.f + __expf(-v));
            }
        }
    }
}

// ---------------- main: deformable sample -> f16 v_dot2 dot (R16-proven) ----------------
__global__ __launch_bounds__(256, 6) void k_main(
    const float* __restrict__ x_t, const float* __restrict__ offs,
    const float* __restrict__ mask, const _Float16* __restrict__ Wh,
    float* __restrict__ out) {
    __shared__ __align__(16) _Float16 a_lds[16 * AHSTRIDE];   // 18688 B; reused as outst
    __shared__ int    pi3[144 * 3];                           // lt, rb, dy
    __shared__ float4 pg4[144];

    int blk = blockIdx.x;
    int b  = blk & 7;                  // XCD swizzle: one batch per XCD
    int rem = blk >> 3;
    int h  = rem >> 3;
    int w0 = (rem & 7) * 16;
    int tid = threadIdx.x;

    // phase 1: sampling coords for 16 pos x 9 pts (proven math)
    if (tid < 144) {
        int e = tid;
        int pos = e / 9, n = e - pos * 9;
        int w = w0 + pos;
        int idx = ((b * 128 + h) * 128 + w);
        float ox = offs[idx * 18 + n];
        float oy = offs[idx * 18 + 9 + n];
        float mv = mask[idx * 9 + n];
        float px = ox + (float)(h + n / 3);
        float py = oy + (float)(w + n % 3);
        float flx = floorf(px), fly = floorf(py);
        float qltx = fminf(fmaxf(flx, 0.f), 129.f);
        float qlty = fminf(fmaxf(fly, 0.f), 129.f);
        float qrbx = fminf(fmaxf(flx + 1.f, 0.f), 129.f);
        float qrby = fminf(fmaxf(fly + 1.f, 0.f), 129.f);
        float pxc = fminf(fmaxf(px, 0.f), 129.f);
        float pyc = fminf(fmaxf(py, 0.f), 129.f);
        float glt = (1.f + qltx - pxc) * (1.f + qlty - pyc);
        float grb = (1.f - qrbx + pxc) * (1.f - qrby + pyc);
        float glb = (1.f + qltx - pxc) * (1.f - qrby + pyc);
        float grt = (1.f - qrbx + pxc) * (1.f + qlty - pyc);
        int ix_lt = (int)qltx, iy_lt = (int)qlty, ix_rb = (int)qrbx, iy_rb = (int)qrby;
        pi3[e * 3 + 0] = (ix_lt * 130 + iy_lt) * 64;
        pi3[e * 3 + 1] = (ix_rb * 130 + iy_rb) * 64;
        pi3[e * 3 + 2] = (iy_rb - iy_lt) * 64;
        pg4[e] = make_float4(glt * mv, grb * mv, glb * mv, grt * mv);
    }
    __syncthreads();

    // phase 2: gather+blend, a_lds[pos][k' = n*64 + ci] in f16 (proven pattern)
    {
        const float* xb = x_t + (size_t)b * 130 * 130 * 64;
        int ci = tid & 63;
        for (int it = 0; it < 36; ++it) {
            int point = (tid >> 6) + it * 4;
            int pos = (point * 456) >> 12;          // point/9, exact for point<288
            int n = point - pos * 9;
            int lt = pi3[point * 3 + 0];
            int rb = pi3[point * 3 + 1];
            int dy = pi3[point * 3 + 2];
            float4 g = pg4[point];
            float v = g.x * xb[lt + ci] + g.y * xb[rb + ci] +
                      g.z * xb[lt + dy + ci] + g.w * xb[rb - dy + ci];
            a_lds[pos * AHSTRIDE + n * 64 + ci] = (_Float16)v;
        }
    }
    __syncthreads();

    // phase 3: f16 dot2. lane = co (+64), wave pg = pos group of 4.
    int lane = tid & 63, pg = tid >> 6;
    const uint4* W4 = (const uint4*)Wh;              // [(k8*128 + co)] = 8 f16
    float acc0[4] = {0.f, 0.f, 0.f, 0.f};
    float acc1[4] = {0.f, 0.f, 0.f, 0.f};

    uint4 wc0 = W4[lane];
    uint4 wc1 = W4[lane + 64];
    #pragma unroll 2
    for (int k8 = 0; k8 < 72; ++k8) {
        uint4 wn0 = W4[(k8 + 1) * 128 + lane];
        uint4 wn1 = W4[(k8 + 1) * 128 + lane + 64];
        h2 w00 = __builtin_bit_cast(h2, wc0.x), w01 = __builtin_bit_cast(h2, wc0.y),
           w02 = __builtin_bit_cast(h2, wc0.z), w03 = __builtin_bit_cast(h2, wc0.w);
        h2 w10 = __builtin_bit_cast(h2, wc1.x), w11 = __builtin_bit_cast(h2, wc1.y),
           w12 = __builtin_bit_cast(h2, wc1.z), w13 = __builtin_bit_cast(h2, wc1.w);
        #pragma unroll
        for (int p = 0; p < 4; ++p) {
            uint4 a = *(const uint4*)&a_lds[(pg * 4 + p) * AHSTRIDE + k8 * 8];  // broadcast
            h2 a0 = __builtin_bit_cast(h2, a.x), a1 = __builtin_bit_cast(h2, a.y),
               a2 = __builtin_bit_cast(h2, a.z), a3 = __builtin_bit_cast(h2, a.w);
            acc0[p] = __builtin_amdgcn_fdot2(a0, w00, acc0[p], false);
            acc0[p] = __builtin_amdgcn_fdot2(a1, w01, acc0[p], false);
            acc0[p] = __builtin_amdgcn_fdot2(a2, w02, acc0[p], false);
            acc0[p] = __builtin_amdgcn_fdot2(a3, w03, acc0[p], false);
            acc1[p] = __builtin_amdgcn_fdot2(a0, w10, acc1[p], false);
            acc1[p] = __builtin_amdgcn_fdot2(a1, w11, acc1[p], false);
            acc1[p] = __builtin_amdgcn_fdot2(a2, w12, acc1[p], false);
            acc1[p] = __builtin_amdgcn_fdot2(a3, w13, acc1[p], false);
        }
        wc0 = wn0; wc1 = wn1;
    }
    __syncthreads();   // all a_lds reads done before aliasing overwrite

    // epilogue: stage via LDS, then coalesced global stores (proven path)
    float* outst = (float*)a_lds;                    // [128 co][17]
    #pragma unroll
    for (int p = 0; p < 4; ++p) {
        outst[lane * 17 + pg * 4 + p]        = acc0[p];
        outst[(lane + 64) * 17 + pg * 4 + p] = acc1[p];
    }
    __syncthreads();
    for (int e = tid; e < 2048; e += 256) {
        int co2 = e >> 4, wl = e & 15;
        out[((size_t)(b * 128 + co2) * 16384) + h * 128 + w0 + wl] = outst[co2 * 17 + wl];
    }
}

// ---------------- BN stats: one block per (b, co) ----------------
__global__ __launch_bounds__(256) void k_stats(
    const float* __restrict__ out, float* __restrict__ partial) {
    __shared__ float s1[256], s2[256];
    int blk = blockIdx.x;
    const float4* p = (const float4*)(out + (size_t)blk * 16384);
    float a1 = 0.f, a2 = 0.f;
    for (int i = threadIdx.x; i < 4096; i += 256) {
        float4 v = p[i];
        a1 += v.x + v.y + v.z + v.w;
        a2 += v.x * v.x + v.y * v.y + v.z * v.z + v.w * v.w;
    }
    s1[threadIdx.x] = a1; s2[threadIdx.x] = a2;
    __syncthreads();
    for (int s = 128; s > 0; s >>= 1) {
        if (threadIdx.x < (unsigned)s) {
            s1[threadIdx.x] += s1[threadIdx.x + s];
            s2[threadIdx.x] += s2[threadIdx.x + s];
        }
        __syncthreads();
    }
    if (threadIdx.x == 0) { partial[blk] = s1[0]; partial[1024 + blk] = s2[0]; }
}

__global__ void k_finalize(const float* __restrict__ partial, const float* __restrict__ gamma,
                           const float* __restrict__ beta, float* __restrict__ sb) {
    int c = threadIdx.x;
    if (c < 128) {
        float s1 = 0.f, s2 = 0.f;
        for (int b = 0; b < 8; ++b) {
            s1 += partial[b * 128 + c];
            s2 += partial[1024 + b * 128 + c];
        }
        const float M = 131072.f;
        float mean = s1 / M;
        float var = fmaxf(s2 / M - mean * mean, 0.f);
        float sc = gamma[c] * rsqrtf(var + 1e-5f);
        sb[c] = sc;
        sb[128 + c] = beta[c] - mean * sc;
    }
}

__global__ void k_bnrelu(float* __restrict__ out, const float* __restrict__ sb) {
    int i = blockIdx.x * 256 + threadIdx.x;
    int c = (i >> 12) & 127;
    float4 v = ((float4*)out)[i];
    float sc = sb[c], bi = sb[128 + c];
    v.x = fmaxf(v.x * sc + bi, 0.f);
    v.y = fmaxf(v.y * sc + bi, 0.f);
    v.z = fmaxf(v.z * sc + bi, 0.f);
    v.w = fmaxf(v.w * sc + bi, 0.f);
    ((float4*)out)[i] = v;
}

extern "C" void kernel_launch(void* const* d_in, const int* in_sizes, int n_in,
                              void* d_out, int out_size, void* d_ws, size_t ws_size,
                              hipStream_t stream) {
    const float* x     = (const float*)d_in[0];
    const float* Wp    = (const float*)d_in[1];
    const float* bp    = (const float*)d_in[2];
    const float* Wm    = (const float*)d_in[3];
    const float* bm    = (const float*)d_in[4];
    const float* Wc    = (const float*)d_in[5];
    const float* gamma = (const float*)d_in[6];
    const float* beta  = (const float*)d_in[7];
    float* out = (float*)d_out;
    float* ws  = (float*)d_ws;

    // ws layout (floats)
    float* x_t      = ws;                          // 8,652,800
    _Float16* Wh    = (_Float16*)(x_t + 8652800);  // 73,728 f16 (36,864 f)
    _Float16* Wh27  = (_Float16*)(x_t + 8652800 + 36864);  // 18,688 f16 (9,344 f; slot 36,864 f)
    float* offs     = x_t + 8652800 + 73728;       // 2,359,296
    float* mask     = offs + 2359296;              // 1,179,648
    float* partial  = mask + 1179648;              // 2048
    float* sb       = partial + 2048;              // 256

    k_zero<<<8450, 256, 0, stream>>>((float4*)x_t, 2163200);
    k_pad_transpose<<<1024, 256, 0, stream>>>(x, x_t);
    k_wct<<<288, 256, 0, stream>>>(Wc, Wh);
    k_wpm<<<73, 256, 0, stream>>>(Wp, Wm, Wh27);
    k_offmask<<<4096, 256, 0, stream>>>(x_t, Wh27, bp, bm, offs, mask);
    k_main<<<8192, 256, 0, stream>>>(x_t, offs, mask, Wh, out);
    k_stats<<<1024, 256, 0, stream>>>(out, partial);
    k_finalize<<<1, 128, 0, stream>>>(partial, gamma, beta, sb);
    k_bnrelu<<<16384, 256, 0, stream>>>(out, sb);
}